// Round 5
// baseline (658.950 us; speedup 1.0000x reference)
//
#include <hip/hip_runtime.h>

#define DIM 384
#define NSEG 1024
#define LDA 392         // shorts per LDS A row (384 + 8 pad)
#define NHB 64          // histogram / scatter blocks

typedef __attribute__((ext_vector_type(8))) short bf16x8;
typedef __attribute__((ext_vector_type(4))) float f32x4;

static __device__ __forceinline__ short f2bf(float f) {
    union { float f; unsigned u; } v{f};
    unsigned r = (v.u + 0x7FFFu + ((v.u >> 16) & 1u)) >> 16;
    return (short)r;
}

// ---------------- fused prep: weight packing + per-block partial histograms ----
// pack: pb[((mat*24 + T)*12 + ks)*512 + lane*8 + e]
//         = W[T*16 + (lane&15)][ks*32 + (lane>>4)*8 + e]
#define PACKB ((2 * 24 * 12 * 64) / 1024)   // 36 blocks of 1024

__global__ __launch_bounds__(1024) void prep_kernel(
    const int* __restrict__ ix, int* __restrict__ hist_part,
    const float* __restrict__ fw, const float* __restrict__ gw,
    short* __restrict__ pb, int H) {
    __shared__ int lh[NSEG];
    int b = blockIdx.x;
    int t = threadIdx.x;
    if (b < PACKB) {
        int idx = b * 1024 + t;
        int lane = idx & 63;
        int ks   = (idx >> 6) % 12;
        int T    = ((idx >> 6) / 12) % 24;
        int mat  = idx / (64 * 12 * 24);
        const float* src = mat ? gw : fw;
        int ch = T * 16 + (lane & 15);
        int k0 = ks * 32 + (lane >> 4) * 8;
        short* dst = pb + (size_t)idx * 8;
#pragma unroll
        for (int e = 0; e < 8; e++) dst[e] = f2bf(src[(size_t)ch * DIM + k0 + e]);
    } else {
        int hb = b - PACKB;
        lh[t] = 0;
        __syncthreads();
        int rpb = (H + NHB - 1) / NHB;
        int lo = hb * rpb;
        int hi = lo + rpb; if (hi > H) hi = H;
        for (int i = lo + t; i < hi; i += 1024)
            atomicAdd(&lh[ix[i]], 1);
        __syncthreads();
        hist_part[hb * NSEG + t] = lh[t];
    }
}

// ---------------- scan: sum partial hists + shuffle-based prefix ----------------
__global__ __launch_bounds__(1024) void scan_kernel(
    const int* __restrict__ hist_part, int* __restrict__ seg_start,
    int* __restrict__ cursor) {
    __shared__ int wsum[16];
    int t = threadIdx.x;
    int v = 0;
#pragma unroll 8
    for (int b = 0; b < NHB; b++) v += hist_part[b * NSEG + t];
    int lane = t & 63, wv = t >> 6;
    int s = v;
#pragma unroll
    for (int off = 1; off < 64; off <<= 1) {
        int u = __shfl_up(s, off, 64);
        if (lane >= off) s += u;
    }
    if (lane == 63) wsum[wv] = s;
    __syncthreads();
    if (wv == 0) {
        int ws = (lane < 16) ? wsum[lane] : 0;
#pragma unroll
        for (int off = 1; off < 16; off <<= 1) {
            int u = __shfl_up(ws, off, 64);
            if (lane >= off) ws += u;
        }
        if (lane < 16) wsum[lane] = ws;
    }
    __syncthreads();
    int incl = s + (wv ? wsum[wv - 1] : 0);
    seg_start[t] = incl - v;
    cursor[t]    = incl - v;
    if (t == NSEG - 1) seg_start[NSEG] = incl;
}

// ---------------- scatter: block-local aggregation ----------------
__global__ __launch_bounds__(1024) void scatter_kernel(
    const int* __restrict__ ix, int* __restrict__ cursor,
    int* __restrict__ order, int H) {
    __shared__ int lbase[NSEG];
    __shared__ int lcur[NSEG];
    int t = threadIdx.x;
    int rpb = (H + gridDim.x - 1) / gridDim.x;
    int lo = blockIdx.x * rpb;
    int hi = lo + rpb; if (hi > H) hi = H;
    lbase[t] = 0;
    __syncthreads();
    for (int i = lo + t; i < hi; i += 1024)
        atomicAdd(&lbase[ix[i]], 1);
    __syncthreads();
    int c = lbase[t];
    int base = (c > 0) ? atomicAdd(&cursor[t], c) : 0;
    __syncthreads();
    lbase[t] = base;
    lcur[t] = 0;
    __syncthreads();
    for (int i = lo + t; i < hi; i += 1024) {
        int sg = ix[i];
        int p = lbase[sg] + atomicAdd(&lcur[sg], 1);
        order[p] = i;
    }
}

// ---------------- per-segment GEMM + softmax reduce (v5) ----------------
// Grid = NSEG blocks of 512 thr (8 waves); block s owns ALL rows of segment s
// (sorted positions seg_start[s]..seg_start[s+1]) -> EXCLUSIVE den/num rows:
// plain stores, zero atomics, no LDS accumulator, no memset.
// Loop over 32-row chunks, double-buffered A in LDS, ONE barrier per chunk
// (v4 had 5/block + one-shot block lifecycle = fixed 29 us/block latency).
// Wave w: channels 48w..48w+48 (tiles 3w..3w+2), BOTH mats. den/num partials
// accumulate in 6 regs/thread across chunks; final cross-q shfl reduce.
__global__ __launch_bounds__(512, 4) void seg_gemm_seg(
    const float* __restrict__ x, const short* __restrict__ pb,
    const float* __restrict__ f_b, const float* __restrict__ g_b,
    const int* __restrict__ order, const int* __restrict__ seg_start,
    float* __restrict__ den, float* __restrict__ num) {
    const int s = blockIdx.x;
    const int b = seg_start[s];
    const int e = seg_start[s + 1];
    const int len = e - b;
    const int nch = (len + 31) >> 5;

    const int tid  = threadIdx.x;
    const int lane = tid & 63;
    const int wave = tid >> 6;
    const int n    = lane & 15;
    const int q    = lane >> 4;
    const int cb   = wave * 48;

    __shared__ short As[2][32 * LDA];   // 2 x 25088 B

    const int r  = tid >> 4;   // staging row 0..31 (16 threads per row)
    const int c6 = tid & 15;

    float fbv[3], gbv[3];
#pragma unroll
    for (int t = 0; t < 3; t++) {
        fbv[t] = f_b[cb + t * 16 + n];
        gbv[t] = g_b[cb + t * 16 + n];
    }

    float sw[3] = {0.f, 0.f, 0.f}, sf[3] = {0.f, 0.f, 0.f};

    // ---- prologue: stage chunk 0 into buf 0 ----
    if (nch > 0) {
        f32x4 sv[6];
#pragma unroll
        for (int i = 0; i < 6; i++) sv[i] = (f32x4){0.f, 0.f, 0.f, 0.f};
        int r0 = b + r;
        if (r0 < e) {
            int gr = order[r0];
            const f32x4* xr = (const f32x4*)(x + (size_t)gr * DIM);
#pragma unroll
            for (int i = 0; i < 6; i++) sv[i] = __builtin_nontemporal_load(xr + c6 + 16 * i);
        }
        short* dst = &As[0][r * LDA];
#pragma unroll
        for (int i = 0; i < 6; i++) {
            short4 sx = { f2bf(sv[i][0]), f2bf(sv[i][1]), f2bf(sv[i][2]), f2bf(sv[i][3]) };
            *(short4*)&dst[(c6 + 16 * i) * 4] = sx;
        }
        __syncthreads();
    }

    for (int c = 0; c < nch; c++) {
        const int cur = c & 1;
        const bool hn = (c + 1) < nch;

        // T14 issue-early: prefetch next chunk's rows (land during MFMA+epilogue)
        f32x4 sv[6];
#pragma unroll
        for (int i = 0; i < 6; i++) sv[i] = (f32x4){0.f, 0.f, 0.f, 0.f};
        if (hn) {
            int r2 = b + (c + 1) * 32 + r;
            if (r2 < e) {
                int gr = order[r2];
                const f32x4* xr = (const f32x4*)(x + (size_t)gr * DIM);
#pragma unroll
                for (int i = 0; i < 6; i++) sv[i] = __builtin_nontemporal_load(xr + c6 + 16 * i);
            }
        }

        f32x4 accf[2][3], accg[2][3];
#pragma unroll
        for (int rt = 0; rt < 2; rt++)
#pragma unroll
            for (int t = 0; t < 3; t++) {
                accf[rt][t] = (f32x4){0.f, 0.f, 0.f, 0.f};
                accg[rt][t] = (f32x4){0.f, 0.f, 0.f, 0.f};
            }

#pragma unroll
        for (int ks = 0; ks < 12; ks++) {
            bf16x8 a[2];
#pragma unroll
            for (int rt = 0; rt < 2; rt++)
                a[rt] = *(const bf16x8*)&As[cur][(rt * 16 + n) * LDA + ks * 32 + q * 8];
#pragma unroll
            for (int t = 0; t < 3; t++) {
                int Tg = wave * 3 + t;
                bf16x8 bfr = *(const bf16x8*)(pb + ((size_t)((0 * 24 + Tg) * 12 + ks)) * 512 + lane * 8);
                bf16x8 bgr = *(const bf16x8*)(pb + ((size_t)((1 * 24 + Tg) * 12 + ks)) * 512 + lane * 8);
#pragma unroll
                for (int rt = 0; rt < 2; rt++) {
                    accf[rt][t] = __builtin_amdgcn_mfma_f32_16x16x32_bf16(a[rt], bfr, accf[rt][t], 0, 0, 0);
                    accg[rt][t] = __builtin_amdgcn_mfma_f32_16x16x32_bf16(a[rt], bgr, accg[rt][t], 0, 0, 0);
                }
            }
        }

        // ---- epilogue: accumulate into registers (VALU hides prefetch) ----
        const int rowbase = c * 32;
#pragma unroll
        for (int t = 0; t < 3; t++) {
#pragma unroll
            for (int rt = 0; rt < 2; rt++) {
#pragma unroll
                for (int rr = 0; rr < 4; rr++) {
                    int m = rt * 16 + q * 4 + rr;
                    float gx = accg[rt][t][rr] + gbv[t];
                    gx = fmaxf(-50.f, fminf(50.f, gx));
                    float w = __expf(gx);
                    float wv = (rowbase + m < len) ? w : 0.f;
                    sw[t] += wv;
                    sf[t] += (accf[rt][t][rr] + fbv[t]) * wv;
                }
            }
        }

        // write-late: next chunk's A into the other buffer
        if (hn) {
            short* dst = &As[cur ^ 1][r * LDA];
#pragma unroll
            for (int i = 0; i < 6; i++) {
                short4 sx = { f2bf(sv[i][0]), f2bf(sv[i][1]), f2bf(sv[i][2]), f2bf(sv[i][3]) };
                *(short4*)&dst[(c6 + 16 * i) * 4] = sx;
            }
        }
        __syncthreads();
    }

    // ---- cross-q reduce and plain store ----
#pragma unroll
    for (int t = 0; t < 3; t++) {
        float d  = sw[t], nm = sf[t];
        d  += __shfl_xor(d, 16, 64);  d  += __shfl_xor(d, 32, 64);
        nm += __shfl_xor(nm, 16, 64); nm += __shfl_xor(nm, 32, 64);
        if (q == 0) {
            den[(size_t)s * DIM + cb + t * 16 + n] = d;
            num[(size_t)s * DIM + cb + t * 16 + n] = nm;
        }
    }
}

// ---------------- small h GEMM: z = (num/den) @ h_w^T + h_b (fp32) ----------------
__global__ __launch_bounds__(256) void hgemm_kernel(
    const float* __restrict__ num, const float* __restrict__ den,
    const float* __restrict__ h_w, const float* __restrict__ h_b,
    float* __restrict__ z) {
    const int m0 = blockIdx.x * 64;
    const int c0 = blockIdx.y * 64;
    const int tid = threadIdx.x;
    const int ty = tid >> 4, tx = tid & 15;
    __shared__ float As[16][64];
    __shared__ float Bs[16][64];
    float acc[4][4];
#pragma unroll
    for (int i = 0; i < 4; i++)
#pragma unroll
        for (int j = 0; j < 4; j++) acc[i][j] = 0.f;

    for (int k0 = 0; k0 < DIM; k0 += 16) {
        __syncthreads();
        {
            int m  = tid >> 2;
            int kq = (tid & 3) << 2;
            size_t idx = (size_t)(m0 + m) * DIM + k0 + kq;
            float4 v = *(const float4*)(num + idx);
            float4 d = *(const float4*)(den + idx);
            v.x /= fmaxf(d.x, 1e-9f); v.y /= fmaxf(d.y, 1e-9f);
            v.z /= fmaxf(d.z, 1e-9f); v.w /= fmaxf(d.w, 1e-9f);
            As[kq + 0][m] = v.x; As[kq + 1][m] = v.y;
            As[kq + 2][m] = v.z; As[kq + 3][m] = v.w;
            float4 w = *(const float4*)(h_w + (size_t)(c0 + m) * DIM + k0 + kq);
            Bs[kq + 0][m] = w.x; Bs[kq + 1][m] = w.y;
            Bs[kq + 2][m] = w.z; Bs[kq + 3][m] = w.w;
        }
        __syncthreads();
#pragma unroll
        for (int kk = 0; kk < 16; kk++) {
            float4 a4 = *(const float4*)&As[kk][ty * 4];
            float4 b4 = *(const float4*)&Bs[kk][tx * 4];
            float a[4] = { a4.x, a4.y, a4.z, a4.w };
            float b[4] = { b4.x, b4.y, b4.z, b4.w };
#pragma unroll
            for (int i = 0; i < 4; i++)
#pragma unroll
                for (int j = 0; j < 4; j++) acc[i][j] += a[i] * b[j];
        }
    }
#pragma unroll
    for (int i = 0; i < 4; i++)
#pragma unroll
        for (int j = 0; j < 4; j++)
            z[(size_t)(m0 + ty * 4 + i) * DIM + c0 + tx * 4 + j] = acc[i][j] + h_b[c0 + tx * 4 + j];
}

// ---------------- gather: out[i] = z[ix[i]] ----------------
__global__ void gather_kernel(const int* __restrict__ ix, const f32x4* __restrict__ z,
                              f32x4* __restrict__ out, int H) {
    int t = blockIdx.x * blockDim.x + threadIdx.x;
    int total = H * (DIM / 4);
    if (t < total) {
        int i = t / (DIM / 4);
        int qq = t - i * (DIM / 4);
        f32x4 v = z[(size_t)ix[i] * (DIM / 4) + qq];
        __builtin_nontemporal_store(v, out + (size_t)i * (DIM / 4) + qq);
    }
}

extern "C" void kernel_launch(void* const* d_in, const int* in_sizes, int n_in,
                              void* d_out, int out_size, void* d_ws, size_t ws_size,
                              hipStream_t stream) {
    const float* x   = (const float*)d_in[0];
    const int*   ix  = (const int*)d_in[1];
    const float* f_w = (const float*)d_in[2];
    const float* f_b = (const float*)d_in[3];
    const float* g_w = (const float*)d_in[4];
    const float* g_b = (const float*)d_in[5];
    const float* h_w = (const float*)d_in[6];
    const float* h_b = (const float*)d_in[7];
    float* out = (float*)d_out;
    const int H = in_sizes[0] / DIM;

    char* w = (char*)d_ws;
    int* hist_part = (int*)w;   w += NHB * NSEG * 4;           // 256 KB partial hists
    int* seg_start = (int*)w;   w += 8192;                     // 1025 ints (padded)
    int* cursor    = (int*)w;   w += 4096;                     // 1024 ints
    int* order     = (int*)w;   w += (size_t)H * 4;            // H ints
    float* den_acc = (float*)w; w += (size_t)NSEG * DIM * 4;   // fully written (no memset)
    float* num_acc = (float*)w; w += (size_t)NSEG * DIM * 4;
    float* z       = (float*)w; w += (size_t)NSEG * DIM * 4;
    short* pb      = (short*)w;                                // packed f+g weights

    prep_kernel<<<PACKB + NHB, 1024, 0, stream>>>(ix, hist_part, f_w, g_w, pb, H);
    scan_kernel<<<1, NSEG, 0, stream>>>(hist_part, seg_start, cursor);
    scatter_kernel<<<NHB, 1024, 0, stream>>>(ix, cursor, order, H);
    seg_gemm_seg<<<NSEG, 512, 0, stream>>>(x, pb, f_b, g_b, order, seg_start,
                                           den_acc, num_acc);
    hgemm_kernel<<<dim3(NSEG / 64, DIM / 64), 256, 0, stream>>>(num_acc, den_acc,
                                                                h_w, h_b, z);
    gather_kernel<<<(H * (DIM / 4) + 255) / 256, 256, 0, stream>>>(
        ix, (const f32x4*)z, (f32x4*)out, H);
}

// Round 6
// 307.789 us; speedup vs baseline: 2.1409x; 2.1409x over previous
//
#include <hip/hip_runtime.h>

#define DIM 384
#define NSEG 1024
#define CHUNK 32        // rows per block
#define LDA 392         // shorts per LDS A row (384 + 8 pad)
#define MAXLS 8         // LDS segment slots per chunk (32-row sorted window spans ~1-2)
#define NHB 16          // histogram blocks

typedef __attribute__((ext_vector_type(8))) short bf16x8;
typedef __attribute__((ext_vector_type(4))) float f32x4;

static __device__ __forceinline__ short f2bf(float f) {
    union { float f; unsigned u; } v{f};
    unsigned r = (v.u + 0x7FFFu + ((v.u >> 16) & 1u)) >> 16;
    return (short)r;
}

// ---------------- fused prep: weight packing + per-block partial histograms ----
// pack: pb[((mat*24 + T)*12 + ks)*512 + lane*8 + e]
//         = W[T*16 + (lane&15)][ks*32 + (lane>>4)*8 + e]
#define PACKB ((2 * 24 * 12 * 64) / 1024)   // 36 blocks of 1024

__global__ __launch_bounds__(1024) void prep_kernel(
    const int* __restrict__ ix, int* __restrict__ hist_part,
    const float* __restrict__ fw, const float* __restrict__ gw,
    short* __restrict__ pb, int H) {
    __shared__ int lh[NSEG];
    int b = blockIdx.x;
    int t = threadIdx.x;
    if (b < PACKB) {
        int idx = b * 1024 + t;
        int lane = idx & 63;
        int ks   = (idx >> 6) % 12;
        int T    = ((idx >> 6) / 12) % 24;
        int mat  = idx / (64 * 12 * 24);
        const float* src = mat ? gw : fw;
        int ch = T * 16 + (lane & 15);
        int k0 = ks * 32 + (lane >> 4) * 8;
        short* dst = pb + (size_t)idx * 8;
#pragma unroll
        for (int e = 0; e < 8; e++) dst[e] = f2bf(src[(size_t)ch * DIM + k0 + e]);
    } else {
        int hb = b - PACKB;
        lh[t] = 0;
        __syncthreads();
        int rpb = (H + NHB - 1) / NHB;
        int lo = hb * rpb;
        int hi = lo + rpb; if (hi > H) hi = H;
        for (int i = lo + t; i < hi; i += 1024)
            atomicAdd(&lh[ix[i]], 1);
        __syncthreads();
        hist_part[hb * NSEG + t] = lh[t];
    }
}

// ---------------- scan: sum partial hists + shuffle-based prefix ----------------
__global__ __launch_bounds__(1024) void scan_kernel(
    const int* __restrict__ hist_part, int* __restrict__ seg_start,
    int* __restrict__ cursor) {
    __shared__ int wsum[16];
    int t = threadIdx.x;
    int v = 0;
#pragma unroll
    for (int b = 0; b < NHB; b++) v += hist_part[b * NSEG + t];
    int lane = t & 63, wv = t >> 6;
    int s = v;
#pragma unroll
    for (int off = 1; off < 64; off <<= 1) {
        int u = __shfl_up(s, off, 64);
        if (lane >= off) s += u;
    }
    if (lane == 63) wsum[wv] = s;
    __syncthreads();
    if (wv == 0) {
        int ws = (lane < 16) ? wsum[lane] : 0;
#pragma unroll
        for (int off = 1; off < 16; off <<= 1) {
            int u = __shfl_up(ws, off, 64);
            if (lane >= off) ws += u;
        }
        if (lane < 16) wsum[lane] = ws;
    }
    __syncthreads();
    int incl = s + (wv ? wsum[wv - 1] : 0);
    seg_start[t] = incl - v;
    cursor[t]    = incl - v;
    if (t == NSEG - 1) seg_start[NSEG] = incl;
}

// ---------------- scatter: block-local aggregation (kills atomic contention) ----
__global__ __launch_bounds__(1024) void scatter_kernel(
    const int* __restrict__ ix, int* __restrict__ cursor,
    int* __restrict__ order, int H) {
    __shared__ int lbase[NSEG];
    __shared__ int lcur[NSEG];
    int t = threadIdx.x;
    int rpb = (H + gridDim.x - 1) / gridDim.x;
    int lo = blockIdx.x * rpb;
    int hi = lo + rpb; if (hi > H) hi = H;
    lbase[t] = 0;
    __syncthreads();
    for (int i = lo + t; i < hi; i += 1024)
        atomicAdd(&lbase[ix[i]], 1);
    __syncthreads();
    int c = lbase[t];
    int base = (c > 0) ? atomicAdd(&cursor[t], c) : 0;
    __syncthreads();
    lbase[t] = base;
    lcur[t] = 0;
    __syncthreads();
    for (int i = lo + t; i < hi; i += 1024) {
        int sg = ix[i];
        int p = lbase[sg] + atomicAdd(&lcur[sg], 1);
        order[p] = i;
    }
}

// ---------------- fused chunk GEMM + segmented softmax reduce (v6) ----------------
// = v4 (312 us) with ONE change: x staging loads are REGULAR cached loads, not
// nontemporal. v1/v3/v4 all pinned at FETCH/dur ~450-500 GB/s: the nt hint
// evicted x from L3 every rep, so the kernel was HBM-supply-bound on scattered
// row refetch. Working set (x 100MB + out 100MB + misc) fits the 256MB L3;
// cached loads keep x L3-resident across reps. (out's store in gather KEEPS nt
// so the write-once output can't evict x.)
__global__ __launch_bounds__(512, 4) void seg_gemm_chunk(
    const float* __restrict__ x, const short* __restrict__ pb,
    const float* __restrict__ f_b, const float* __restrict__ g_b,
    const int* __restrict__ order, const int* __restrict__ ix,
    float* __restrict__ den_acc, float* __restrict__ num_acc) {
    const int chunk0 = blockIdx.x * CHUNK;
    const int tid  = threadIdx.x;
    const int lane = tid & 63;
    const int wave = tid >> 6;
    const int n    = lane & 15;
    const int q    = lane >> 4;
    const int cb   = wave * 48;

    __shared__ short As[CHUNK * LDA];     // 25088 B; aliased as float acc later
    __shared__ int   segrow[CHUNK];

    // ---- stage 32 rows of x (sorted order) as bf16; record segment ids ----
    {
        int r  = tid >> 4;   // 0..31 (16 threads per row)
        int c6 = tid & 15;
        int gr = order[chunk0 + r];
        if (c6 == 0) segrow[r] = ix[gr];
        const f32x4* xr = (const f32x4*)(x + (size_t)gr * DIM);
        short* dst = &As[r * LDA];
#pragma unroll
        for (int i = 0; i < 6; i++) {
            f32x4 v = xr[c6 + 16 * i];           // cached load (nt removed)
            short4 s = { f2bf(v[0]), f2bf(v[1]), f2bf(v[2]), f2bf(v[3]) };
            *(short4*)&dst[(c6 + 16 * i) * 4] = s;
        }
    }
    __syncthreads();

    float fbv[3], gbv[3];
#pragma unroll
    for (int t = 0; t < 3; t++) {
        fbv[t] = f_b[cb + t * 16 + n];
        gbv[t] = g_b[cb + t * 16 + n];
    }

    f32x4 accf[2][3], accg[2][3];
#pragma unroll
    for (int rt = 0; rt < 2; rt++)
#pragma unroll
        for (int t = 0; t < 3; t++) {
            accf[rt][t] = (f32x4){0.f, 0.f, 0.f, 0.f};
            accg[rt][t] = (f32x4){0.f, 0.f, 0.f, 0.f};
        }

#pragma unroll
    for (int ks = 0; ks < 12; ks++) {
        bf16x8 a[2];
#pragma unroll
        for (int rt = 0; rt < 2; rt++)
            a[rt] = *(const bf16x8*)&As[(rt * 16 + n) * LDA + ks * 32 + q * 8];
#pragma unroll
        for (int t = 0; t < 3; t++) {
            int Tg = wave * 3 + t;
            bf16x8 bfr = *(const bf16x8*)(pb + ((size_t)((0 * 24 + Tg) * 12 + ks)) * 512 + lane * 8);
            bf16x8 bgr = *(const bf16x8*)(pb + ((size_t)((1 * 24 + Tg) * 12 + ks)) * 512 + lane * 8);
#pragma unroll
            for (int rt = 0; rt < 2; rt++) {
                accf[rt][t] = __builtin_amdgcn_mfma_f32_16x16x32_bf16(a[rt], bfr, accf[rt][t], 0, 0, 0);
                accg[rt][t] = __builtin_amdgcn_mfma_f32_16x16x32_bf16(a[rt], bgr, accg[rt][t], 0, 0, 0);
            }
        }
    }

    // ---- epilogue: segmented reduce via 8-slot LDS accumulator ----
    const int s0 = segrow[0];
    __syncthreads();                       // all A reads done; reuse LDS
    float* accs = (float*)As;              // [MAXLS][DIM][2] = 24576 B <= 25088
    for (int i = tid; i < MAXLS * DIM * 2; i += 512) accs[i] = 0.f;
    __syncthreads();

#pragma unroll
    for (int t = 0; t < 3; t++) {
        int ch = cb + t * 16 + n;
        float rw = 0.f, rf = 0.f;
        int cur = -1;
#pragma unroll
        for (int rt = 0; rt < 2; rt++) {
#pragma unroll
            for (int r = 0; r < 4; r++) {
                int m  = rt * 16 + q * 4 + r;       // ascending in (rt, r)
                int ls = segrow[m] - s0;
                if (ls != cur) {
                    if (cur >= 0) {
                        if (cur < MAXLS) {
                            atomicAdd(&accs[(cur * DIM + ch) * 2 + 0], rw);
                            atomicAdd(&accs[(cur * DIM + ch) * 2 + 1], rf);
                        } else {
                            atomicAdd(&den_acc[(size_t)(s0 + cur) * DIM + ch], rw);
                            atomicAdd(&num_acc[(size_t)(s0 + cur) * DIM + ch], rf);
                        }
                    }
                    cur = ls; rw = 0.f; rf = 0.f;
                }
                float gx = accg[rt][t][r] + gbv[t];
                gx = fmaxf(-50.f, fminf(50.f, gx));
                float w = __expf(gx);
                rw += w;
                rf += (accf[rt][t][r] + fbv[t]) * w;
            }
        }
        if (cur < MAXLS) {
            atomicAdd(&accs[(cur * DIM + ch) * 2 + 0], rw);
            atomicAdd(&accs[(cur * DIM + ch) * 2 + 1], rf);
        } else {
            atomicAdd(&den_acc[(size_t)(s0 + cur) * DIM + ch], rw);
            atomicAdd(&num_acc[(size_t)(s0 + cur) * DIM + ch], rf);
        }
    }
    __syncthreads();

    // ---- flush used LDS slots to global partials ----
    int nls = segrow[CHUNK - 1] - s0 + 1;
    if (nls > MAXLS) nls = MAXLS;
    for (int i = tid; i < nls * DIM; i += 512) {
        int ls = i / DIM, ch = i - ls * DIM;
        float dw = accs[(ls * DIM + ch) * 2 + 0];
        float dn = accs[(ls * DIM + ch) * 2 + 1];
        if (dw != 0.f || dn != 0.f) {
            atomicAdd(&den_acc[(size_t)(s0 + ls) * DIM + ch], dw);
            atomicAdd(&num_acc[(size_t)(s0 + ls) * DIM + ch], dn);
        }
    }
}

// ---------------- small h GEMM: z = (num/den) @ h_w^T + h_b (fp32) ----------------
__global__ __launch_bounds__(256) void hgemm_kernel(
    const float* __restrict__ num, const float* __restrict__ den,
    const float* __restrict__ h_w, const float* __restrict__ h_b,
    float* __restrict__ z) {
    const int m0 = blockIdx.x * 64;
    const int c0 = blockIdx.y * 64;
    const int tid = threadIdx.x;
    const int ty = tid >> 4, tx = tid & 15;
    __shared__ float As[16][64];
    __shared__ float Bs[16][64];
    float acc[4][4];
#pragma unroll
    for (int i = 0; i < 4; i++)
#pragma unroll
        for (int j = 0; j < 4; j++) acc[i][j] = 0.f;

    for (int k0 = 0; k0 < DIM; k0 += 16) {
        __syncthreads();
        {
            int m  = tid >> 2;
            int kq = (tid & 3) << 2;
            size_t idx = (size_t)(m0 + m) * DIM + k0 + kq;
            float4 v = *(const float4*)(num + idx);
            float4 d = *(const float4*)(den + idx);
            v.x /= fmaxf(d.x, 1e-9f); v.y /= fmaxf(d.y, 1e-9f);
            v.z /= fmaxf(d.z, 1e-9f); v.w /= fmaxf(d.w, 1e-9f);
            As[kq + 0][m] = v.x; As[kq + 1][m] = v.y;
            As[kq + 2][m] = v.z; As[kq + 3][m] = v.w;
            float4 w = *(const float4*)(h_w + (size_t)(c0 + m) * DIM + k0 + kq);
            Bs[kq + 0][m] = w.x; Bs[kq + 1][m] = w.y;
            Bs[kq + 2][m] = w.z; Bs[kq + 3][m] = w.w;
        }
        __syncthreads();
#pragma unroll
        for (int kk = 0; kk < 16; kk++) {
            float4 a4 = *(const float4*)&As[kk][ty * 4];
            float4 b4 = *(const float4*)&Bs[kk][tx * 4];
            float a[4] = { a4.x, a4.y, a4.z, a4.w };
            float b[4] = { b4.x, b4.y, b4.z, b4.w };
#pragma unroll
            for (int i = 0; i < 4; i++)
#pragma unroll
                for (int j = 0; j < 4; j++) acc[i][j] += a[i] * b[j];
        }
    }
#pragma unroll
    for (int i = 0; i < 4; i++)
#pragma unroll
        for (int j = 0; j < 4; j++)
            z[(size_t)(m0 + ty * 4 + i) * DIM + c0 + tx * 4 + j] = acc[i][j] + h_b[c0 + tx * 4 + j];
}

// ---------------- gather: out[i] = z[ix[i]] (nt STORE kept: protect x in L3) ----
__global__ void gather_kernel(const int* __restrict__ ix, const f32x4* __restrict__ z,
                              f32x4* __restrict__ out, int H) {
    int t = blockIdx.x * blockDim.x + threadIdx.x;
    int total = H * (DIM / 4);
    if (t < total) {
        int i = t / (DIM / 4);
        int qq = t - i * (DIM / 4);
        f32x4 v = z[(size_t)ix[i] * (DIM / 4) + qq];
        __builtin_nontemporal_store(v, out + (size_t)i * (DIM / 4) + qq);
    }
}

extern "C" void kernel_launch(void* const* d_in, const int* in_sizes, int n_in,
                              void* d_out, int out_size, void* d_ws, size_t ws_size,
                              hipStream_t stream) {
    const float* x   = (const float*)d_in[0];
    const int*   ix  = (const int*)d_in[1];
    const float* f_w = (const float*)d_in[2];
    const float* f_b = (const float*)d_in[3];
    const float* g_w = (const float*)d_in[4];
    const float* g_b = (const float*)d_in[5];
    const float* h_w = (const float*)d_in[6];
    const float* h_b = (const float*)d_in[7];
    float* out = (float*)d_out;
    const int H = in_sizes[0] / DIM;

    char* w = (char*)d_ws;
    int* hist_part = (int*)w;   w += NHB * NSEG * 4;           // 64 KB partial hists
    int* seg_start = (int*)w;   w += 8192;                     // 1025 ints (padded)
    int* cursor    = (int*)w;   w += 4096;                     // 1024 ints
    int* order     = (int*)w;   w += (size_t)H * 4;            // H ints
    float* den_acc = (float*)w; w += (size_t)NSEG * DIM * 4;   // zeroed below
    float* num_acc = (float*)w; w += (size_t)NSEG * DIM * 4;   // zeroed below (contiguous)
    float* z       = (float*)w; w += (size_t)NSEG * DIM * 4;
    short* pb      = (short*)w;                                // packed f+g weights

    (void)hipMemsetAsync(den_acc, 0, (size_t)2 * NSEG * DIM * 4, stream);
    prep_kernel<<<PACKB + NHB, 1024, 0, stream>>>(ix, hist_part, f_w, g_w, pb, H);
    scan_kernel<<<1, NSEG, 0, stream>>>(hist_part, seg_start, cursor);
    scatter_kernel<<<NHB, 1024, 0, stream>>>(ix, cursor, order, H);
    seg_gemm_chunk<<<H / CHUNK, 512, 0, stream>>>(x, pb, f_b, g_b, order, ix,
                                                  den_acc, num_acc);
    hgemm_kernel<<<dim3(NSEG / 64, DIM / 64), 256, 0, stream>>>(num_acc, den_acc,
                                                                h_w, h_b, z);
    gather_kernel<<<(H * (DIM / 4) + 255) / 256, 256, 0, stream>>>(
        ix, (const f32x4*)z, (f32x4*)out, H);
}